// Round 5
// baseline (192.186 us; speedup 1.0000x reference)
//
#include <hip/hip_runtime.h>
#include <cstdint>

// VQ-VAE vector quantizer, MI355X (gfx950). Round 9 (resubmit; r4 bench was an
// infra failure -- container acquisition, kernel never ran).
// Evidence r8: nt stores amplified WRITE 36.9->76.7MB, nt loads FETCH->43MB,
// dur 50.5 -- reverted. Six structures all 40-50us with all pipes <15% =>
// waves stalled on VMEM waitcnt (no counter on gfx950). Mechanism:
// in-loop eTe global loads are issued AFTER the B-prefetch burst; the selects'
// wait on ete drains (ordered vmcnt) the entire just-issued prefetch -> every
// slice tail eats full L2 latency (~800cyc under 12.8TB/s B-replication).
// r9 = r7 structure (best measured, ~40us) + three changes ONLY:
//  - eTe -> LDS table (loaded once): in-loop ete = ds_read (lgkmcnt domain,
//    decoupled from vmcnt). Only in-loop VMEM left is the B stream.
//  - 4-deep register prefetch B0..B3 (128 VGPR; free at 2 waves/SIMD --
//    grid 512 = 2 blocks/CU, launch_bounds(256,2) gives 256-reg budget).
//  - per-block slice rotation (blockIdx%16) + explicit (score,idx) tie-break:
//    kills the 2048-wave herd on slice-0 cold lines.
// Floors: MFMA 8.3us, L2-B 14.8us, z-in 5.3, out 5.3. Predict main 22-27us.
// If main >=35: theory dead -> next round runs scaled ablation dispatches.

typedef float f32x4 __attribute__((ext_vector_type(4)));
typedef long  l2    __attribute__((ext_vector_type(2)));
typedef _Float16 f16;
typedef f16 f16x8 __attribute__((ext_vector_type(8)));

#define D_DIM 256
#define K_CODES 1024

__device__ __forceinline__ long pack_fp8x8(float x0, float x1, float x2, float x3,
                                           float x4, float x5, float x6, float x7) {
    int w0 = __builtin_amdgcn_cvt_pk_fp8_f32(x0, x1, 0, false);
    w0     = __builtin_amdgcn_cvt_pk_fp8_f32(x2, x3, w0, true);
    int w1 = __builtin_amdgcn_cvt_pk_fp8_f32(x4, x5, 0, false);
    w1     = __builtin_amdgcn_cvt_pk_fp8_f32(x6, x7, w1, true);
    int2 p = {w0, w1};
    return __builtin_bit_cast(long, p);
}

// ---- Prep (verified r5-r8, unchanged): zero loss slot; emb -> fp8 (x1024) in
// fragment-slice-linear order (16 slices of 64 codes; chunk = ct*256 + t*64 +
// q*16 + m holds k-dims [t*64+q*8,+8) and [t*64+32+q*8,+8) of code
// sp*64+ct*16+m); eTe = 1024*||e||^2 fp32. grid 256 x 256.
__global__ __launch_bounds__(256) void vq_prep(const float* __restrict__ emb,
                                               char* __restrict__ emb8,
                                               float* __restrict__ eTe,
                                               float* __restrict__ loss_slot) {
    const int tid = threadIdx.x, wave = tid >> 6, lane = tid & 63;
    if (blockIdx.x == 0 && tid == 0) *loss_slot = 0.0f;

    if (blockIdx.x < 64) {
        int ch  = blockIdx.x * 256 + tid;     // 16384 chunks
        int sp  = ch >> 10;
        int rem = ch & 1023;
        int ct  = rem >> 8;
        int t   = (rem >> 6) & 3;
        int l   = rem & 63;
        int qq  = l >> 4, mm = l & 15;
        int code = sp * 64 + ct * 16 + mm;
        const float* p = emb + (size_t)code * D_DIM;
        int b0 = t * 64 + qq * 8;
        int b1 = b0 + 32;
        float4 v0 = *(const float4*)(p + b0);
        float4 v1 = *(const float4*)(p + b0 + 4);
        float4 v2 = *(const float4*)(p + b1);
        float4 v3 = *(const float4*)(p + b1 + 4);
        l2 out;
        out.x = pack_fp8x8(v0.x * 1024.f, v0.y * 1024.f, v0.z * 1024.f, v0.w * 1024.f,
                           v1.x * 1024.f, v1.y * 1024.f, v1.z * 1024.f, v1.w * 1024.f);
        out.y = pack_fp8x8(v2.x * 1024.f, v2.y * 1024.f, v2.z * 1024.f, v2.w * 1024.f,
                           v3.x * 1024.f, v3.y * 1024.f, v3.z * 1024.f, v3.w * 1024.f);
        *(l2*)(emb8 + (size_t)ch * 16) = out;
    }

    // eTe: one wave per code, 4 codes per block, pre-scaled by 1024.
    int code = blockIdx.x * 4 + wave;
    float4 v = ((const float4*)(emb + (size_t)code * D_DIM))[lane];
    float s = v.x * v.x + v.y * v.y + v.z * v.z + v.w * v.w;
    #pragma unroll
    for (int off = 32; off >= 1; off >>= 1) s += __shfl_down(s, off);
    if (lane == 0) eTe[code] = 1024.0f * s;
}

// ---- Main kernel -----------------------------------------------------------
__device__ __forceinline__ void loadB(l2 (&B)[16], const l2* __restrict__ gB,
                                      int sl, int lane) {
    const l2* p = gB + (size_t)sl * 1024 + lane;
    #pragma unroll
    for (int j = 0; j < 16; j++) B[j] = p[j * 64];   // 1KB coalesced each
}

// Score one 64-code slice. ete comes from LDS (lgkmcnt domain -- does NOT
// touch vmcnt, so the B prefetch stream stays decoupled). Explicit
// (score, index) tie-break makes the result visit-order independent
// (needed for per-block slice rotation).
__device__ __forceinline__ void computeSlice(const l2 (&B)[16], const long (&A8)[8],
                                             const float* setep, int code0,
                                             int m, float (&best)[4], int (&bidx)[4]) {
    float ete[4];
    #pragma unroll
    for (int ct = 0; ct < 4; ct++) ete[ct] = setep[ct * 16 + m];   // ds_read

    f32x4 acc[4];
    #pragma unroll
    for (int ct = 0; ct < 4; ct++) acc[ct] = (f32x4){0.f, 0.f, 0.f, 0.f};

    __builtin_amdgcn_s_setprio(1);
    #pragma unroll
    for (int t = 0; t < 4; t++) {
        #pragma unroll
        for (int ct = 0; ct < 4; ct++) {
            acc[ct] = __builtin_amdgcn_mfma_f32_16x16x32_fp8_fp8(A8[2*t],   B[ct*4+t].x, acc[ct], 0, 0, 0);
            acc[ct] = __builtin_amdgcn_mfma_f32_16x16x32_fp8_fp8(A8[2*t+1], B[ct*4+t].y, acc[ct], 0, 0, 0);
        }
    }
    __builtin_amdgcn_s_setprio(0);

    #pragma unroll
    for (int ct = 0; ct < 4; ct++) {
        const int code = code0 + ct * 16 + m;
        #pragma unroll
        for (int r = 0; r < 4; r++) {
            float sc = fmaf(-2.0f, acc[ct][r], ete[ct]);
            if (sc < best[r] || (sc == best[r] && code < bidx[r])) {
                best[r] = sc; bidx[r] = code;
            }
        }
    }
}

// Wave-independent: wave = 16 FIXED rows x all 1024 codes; 4-deep register
// prefetch of B slices; slice order rotated per block.
__global__ __launch_bounds__(256, 2) void vq_main6(const float* __restrict__ z,
                                                   const char* __restrict__ emb8,
                                                   const float* __restrict__ eTe,
                                                   const float* __restrict__ emb,
                                                   float* __restrict__ out,
                                                   float* __restrict__ loss_slot,
                                                   float loss_scale) {
    __shared__ float s_ete[K_CODES];     // 4 KB
    __shared__ float s_red[4];

    const int tid  = threadIdx.x;
    const int w    = tid >> 6;
    const int lane = tid & 63;
    const int m    = lane & 15;        // A row / B col (code) / C col
    const int q    = lane >> 4;        // k-group / C row-group
    const int gw   = blockIdx.x * 4 + w;
    const size_t row0 = (size_t)gw * 16;
    const int sl0  = blockIdx.x & 15;  // slice rotation

    const l2* gB = (const l2*)emb8;
    l2 B0[16], B1[16], B2[16], B3[16];
    loadB(B0, gB, sl0, lane);
    loadB(B1, gB, (sl0 + 1) & 15, lane);

    // eTe -> LDS once (in-loop ete reads leave vmcnt alone).
    #pragma unroll
    for (int i = 0; i < 4; i++) s_ete[i * 256 + tid] = eTe[i * 256 + tid];

    // A fragments: this wave's 16 rows -> fp8 (verified r5-r8 layout):
    // lane (q,m) holds row m, k-dims [s*32+q*8, +8) per k-step s.
    long A8[8];
    float zsq = 0.f;
    {
        const float* zr = z + (row0 + m) * D_DIM;
        #pragma unroll
        for (int s = 0; s < 8; s++) {
            const float* p = zr + s * 32 + q * 8;
            float4 v0 = *(const float4*)p;
            float4 v1 = *(const float4*)(p + 4);
            zsq += v0.x * v0.x + v0.y * v0.y + v0.z * v0.z + v0.w * v0.w
                 + v1.x * v1.x + v1.y * v1.y + v1.z * v1.z + v1.w * v1.w;
            A8[s] = pack_fp8x8(v0.x, v0.y, v0.z, v0.w, v1.x, v1.y, v1.z, v1.w);
        }
    }
    __syncthreads();                    // s_ete table ready (one-time drain)

    loadB(B2, gB, (sl0 + 2) & 15, lane);
    loadB(B3, gB, (sl0 + 3) & 15, lane);

    float best[4];
    int   bidx[4];
    #pragma unroll
    for (int r = 0; r < 4; r++) { best[r] = __builtin_inff(); bidx[r] = 0x7fffffff; }

    // 16 slices, 4-deep rotation; only VMEM in loop = B stream (counted vmcnt).
    #pragma unroll 1
    for (int ii = 0; ii < 16; ii += 4) {
        const int s0 = (sl0 + ii) & 15,     s1 = (sl0 + ii + 1) & 15;
        const int s2 = (sl0 + ii + 2) & 15, s3 = (sl0 + ii + 3) & 15;
        computeSlice(B0, A8, &s_ete[s0 * 64], s0 * 64, m, best, bidx);
        if (ii + 4 < 16) loadB(B0, gB, (sl0 + ii + 4) & 15, lane);
        computeSlice(B1, A8, &s_ete[s1 * 64], s1 * 64, m, best, bidx);
        if (ii + 5 < 16) loadB(B1, gB, (sl0 + ii + 5) & 15, lane);
        computeSlice(B2, A8, &s_ete[s2 * 64], s2 * 64, m, best, bidx);
        if (ii + 6 < 16) loadB(B2, gB, (sl0 + ii + 6) & 15, lane);
        computeSlice(B3, A8, &s_ete[s3 * 64], s3 * 64, m, best, bidx);
        if (ii + 7 < 16) loadB(B3, gB, (sl0 + ii + 7) & 15, lane);
    }

    // ONE cross-lane argmin per wave (xor-butterfly within each 16-lane
    // q-group; (score, index) total order -> order-independent result).
    #pragma unroll
    for (int r = 0; r < 4; r++) {
        float b  = best[r];
        int   bi = bidx[r];
        #pragma unroll
        for (int off = 8; off >= 1; off >>= 1) {
            float ob = __shfl_xor(b, off);
            int   oi = __shfl_xor(bi, off);
            if (ob < b || (ob == b && oi < bi)) { b = ob; bi = oi; }
        }
        best[r] = b; bidx[r] = bi;     // uniform within each 16-lane q-group
    }

    // Epilogue per wave: broadcast idx of row (qq*4+r) from lane qq*16,
    // gather emb row (L2-hot, 1KB coalesced), write out row (1KB coalesced).
    float lsum = 0.f;
    float* orow0 = out + row0 * D_DIM + (size_t)lane * 4;
    #pragma unroll
    for (int row = 0; row < 16; row++) {
        const int r  = row & 3;
        const int qq = row >> 2;
        int   bi = __shfl(bidx[r], qq * 16);
        float b  = __shfl(best[r], qq * 16);
        lsum += b;                               // uniform across lanes
        float4 ev = *(const float4*)(emb + (size_t)bi * D_DIM + lane * 4);
        *(float4*)(orow0 + (size_t)row * D_DIM) = ev;
    }

    // loss: sum(z^2) over the wave's rows + sum(best)/1024.
    #pragma unroll
    for (int off = 32; off >= 1; off >>= 1) zsq += __shfl_down(zsq, off);
    if (lane == 0) s_red[w] = zsq + lsum * (1.0f / 1024.0f);
    __syncthreads();
    if (tid == 0)
        atomicAdd(loss_slot, (s_red[0] + s_red[1] + s_red[2] + s_red[3]) * loss_scale);
}

// ---- Fallback (round-2 structure, verified) — only if ws too small. --------
__global__ __launch_bounds__(256) void vq_prep_fb(const float* __restrict__ emb,
                                                  float* __restrict__ eTe,
                                                  float* __restrict__ loss_slot) {
    if (blockIdx.x == 0 && threadIdx.x == 0) *loss_slot = 0.0f;
    if (!eTe) return;
    int gtid = blockIdx.x * 256 + threadIdx.x;
    int code = gtid >> 6;
    int lane = threadIdx.x & 63;
    if (code >= K_CODES) return;
    float4 v = ((const float4*)(emb + (size_t)code * D_DIM))[lane];
    float s = v.x * v.x + v.y * v.y + v.z * v.z + v.w * v.w;
    #pragma unroll
    for (int off = 32; off >= 1; off >>= 1) s += __shfl_down(s, off);
    if (lane == 0) eTe[code] = s;
}

__global__ __launch_bounds__(128) void vq_main_fb(const float* __restrict__ z,
                                                  const float* __restrict__ emb,
                                                  const float* __restrict__ eTe_g,
                                                  float* __restrict__ out,
                                                  float* __restrict__ loss_slot,
                                                  float loss_scale) {
    __shared__ __align__(16) f16 sE[128 * D_DIM];
    __shared__ float s_ete[128];
    __shared__ int   s_idx2[128];
    __shared__ float s_red2[2];

    const int tid  = threadIdx.x;
    const int wave = tid >> 6;
    const int lane = tid & 63;
    const int m    = lane & 15;
    const int q    = lane >> 4;
    const size_t row0 = (size_t)blockIdx.x * 128 + (size_t)wave * 64;

    f16x8 A[4][8];
    #pragma unroll
    for (int st = 0; st < 4; st++) {
        const float* zr = z + (row0 + st * 16 + m) * D_DIM;
        #pragma unroll
        for (int s = 0; s < 8; s++) {
            const float* p = zr + s * 32 + q * 8;
            float4 v0 = *(const float4*)p;
            float4 v1 = *(const float4*)(p + 4);
            f16x8 a = {(f16)v0.x, (f16)v0.y, (f16)v0.z, (f16)v0.w,
                       (f16)v1.x, (f16)v1.y, (f16)v1.z, (f16)v1.w};
            A[st][s] = a;
        }
    }
    float best[4][4]; int bidx[4][4];
    #pragma unroll
    for (int st = 0; st < 4; st++)
        #pragma unroll
        for (int r = 0; r < 4; r++) { best[st][r] = __builtin_inff(); bidx[st][r] = 0; }

    const f16x8* sE8 = (const f16x8*)sE;
    #pragma unroll 1
    for (int sp = 0; sp < 8; sp++) {
        __syncthreads();
        if (eTe_g) s_ete[tid] = 1024.0f * eTe_g[sp * 128 + tid];
        else {
            const float* p = emb + (size_t)(sp * 128 + tid) * D_DIM;
            float ss = 0.f;
            for (int j = 0; j < D_DIM / 4; j++) {
                float4 v = ((const float4*)p)[j];
                ss += v.x * v.x + v.y * v.y + v.z * v.z + v.w * v.w;
            }
            s_ete[tid] = 1024.0f * ss;
        }
        const float* ebase = emb + (size_t)sp * 128 * D_DIM;
        #pragma unroll 4
        for (int it = 0; it < 32; it++) {
            int ch = it * 128 + tid;
            int cc = ((ch >> 9) << 4) | (ch & 15);
            int gg = (ch >> 4) & 31;
            const float* p = ebase + cc * D_DIM + gg * 8;
            float4 v0 = *(const float4*)p;
            float4 v1 = *(const float4*)(p + 4);
            f16x8 h = {(f16)(v0.x * 1024.f), (f16)(v0.y * 1024.f),
                       (f16)(v0.z * 1024.f), (f16)(v0.w * 1024.f),
                       (f16)(v1.x * 1024.f), (f16)(v1.y * 1024.f),
                       (f16)(v1.z * 1024.f), (f16)(v1.w * 1024.f)};
            *(f16x8*)(sE + (size_t)ch * 8) = h;
        }
        __syncthreads();
        for (int ct = 0; ct < 8; ct++) {
            f32x4 acc[4];
            #pragma unroll
            for (int st = 0; st < 4; st++) acc[st] = (f32x4){0.f, 0.f, 0.f, 0.f};
            #pragma unroll
            for (int s = 0; s < 8; s++) {
                f16x8 bh = sE8[ct * 512 + s * 64 + lane];
                #pragma unroll
                for (int st = 0; st < 4; st++)
                    acc[st] = __builtin_amdgcn_mfma_f32_16x16x32_f16(A[st][s], bh, acc[st], 0, 0, 0);
            }
            int codeL = ct * 16 + m;
            float ete = s_ete[codeL];
            int code  = sp * 128 + codeL;
            #pragma unroll
            for (int st = 0; st < 4; st++)
                #pragma unroll
                for (int r = 0; r < 4; r++) {
                    float sc = fmaf(-2.0f, acc[st][r], ete);
                    if (sc < best[st][r]) { best[st][r] = sc; bidx[st][r] = code; }
                }
        }
    }
    #pragma unroll
    for (int st = 0; st < 4; st++)
        #pragma unroll
        for (int r = 0; r < 4; r++) {
            float b = best[st][r]; int bi = bidx[st][r];
            #pragma unroll
            for (int off = 8; off >= 1; off >>= 1) {
                float ob = __shfl_xor(b, off);
                int   oi = __shfl_xor(bi, off);
                if (ob < b || (ob == b && oi < bi)) { b = ob; bi = oi; }
            }
            if (m == 0) s_idx2[wave * 64 + st * 16 + q * 4 + r] = bi;
        }
    __syncthreads();
    float lsum = 0.f;
    #pragma unroll
    for (int st = 0; st < 4; st++) {
        int rl = wave * 64 + st * 16 + m;
        int idxv = s_idx2[rl];
        const float* er = emb + (size_t)idxv * D_DIM;
        float* orow = out + ((size_t)blockIdx.x * 128 + rl) * D_DIM;
        #pragma unroll
        for (int s = 0; s < 8; s++) {
            int dd = s * 32 + q * 8;
            float4 e0 = *(const float4*)(er + dd);
            float4 e1 = *(const float4*)(er + dd + 4);
            *(float4*)(orow + dd)     = e0;
            *(float4*)(orow + dd + 4) = e1;
            f16x8 a = A[st][s];
            float d0 = e0.x - (float)a[0], d1 = e0.y - (float)a[1];
            float d2 = e0.z - (float)a[2], d3 = e0.w - (float)a[3];
            float d4 = e1.x - (float)a[4], d5 = e1.y - (float)a[5];
            float d6 = e1.z - (float)a[6], d7 = e1.w - (float)a[7];
            lsum += d0*d0 + d1*d1 + d2*d2 + d3*d3 + d4*d4 + d5*d5 + d6*d6 + d7*d7;
        }
    }
    #pragma unroll
    for (int off = 32; off >= 1; off >>= 1) lsum += __shfl_down(lsum, off);
    if (lane == 0) s_red2[wave] = lsum;
    __syncthreads();
    if (tid == 0) atomicAdd(loss_slot, (s_red2[0] + s_red2[1]) * loss_scale);
}

extern "C" void kernel_launch(void* const* d_in, const int* in_sizes, int n_in,
                              void* d_out, int out_size, void* d_ws, size_t ws_size,
                              hipStream_t stream) {
    const float* z   = (const float*)d_in[0];
    const float* emb = (const float*)d_in[1];
    float* out = (float*)d_out;
    const int NROWS = in_sizes[0] / D_DIM;              // 32768
    float* loss_slot = out + (size_t)in_sizes[0];
    float loss_scale = 1.25f / (float)in_sizes[0];

    const size_t emb8_bytes = (size_t)K_CODES * D_DIM;  // 256 KB
    const size_t need = emb8_bytes + K_CODES * sizeof(float);

    if (ws_size >= need) {
        char*  emb8 = (char*)d_ws;
        float* eTe  = (float*)((char*)d_ws + emb8_bytes);
        vq_prep<<<256, 256, 0, stream>>>(emb, emb8, eTe, loss_slot);
        vq_main6<<<NROWS / 64, 256, 0, stream>>>(z, emb8, eTe, emb, out, loss_slot, loss_scale);
    } else {
        float* eTe = (ws_size >= K_CODES * sizeof(float)) ? (float*)d_ws : nullptr;
        vq_prep_fb<<<K_CODES / 4, 256, 0, stream>>>(emb, eTe, loss_slot);
        vq_main_fb<<<NROWS / 128, 128, 0, stream>>>(z, emb, eTe, out, loss_slot, loss_scale);
    }
}

// Round 6
// 119.935 us; speedup vs baseline: 1.6024x; 1.6024x over previous
//
#include <hip/hip_runtime.h>
#include <cstdint>

// VQ-VAE vector quantizer, MI355X (gfx950). Round 10.
// Evidence r9: 4-deep prefetch (B0..B3 = 128 regs) blew the 128-VGPR
// allocation -> scratch spill (WRITE 307MB, FETCH 158MB, dur 130-208us).
// eTe->LDS theory never tested (confounded). r9 DID show the chip streams
// 3.6TB/s through this kernel when requests are outstanding -> not a BW wall.
// r10: (a) revert to 2-deep dbuf (~110 live regs, no spill); (b) SPLIT score
// and gather into separate dispatches so rocprof reports per-phase counters
// (no VMEM-wait counter exists on gfx950 -- this is the instrumentation);
// (c) keep eTe->LDS (clean single-variable test of the vmcnt-coupling theory)
// and slice rotation (correctness-verified in r9's passing run).
//  - vq_score: wave = 16 fixed rows x all 1024 codes, Ba/Bb reg dbuf from L2,
//    in-loop VMEM = B stream only; writes idx[32768] (128KB) + loss.
//  - vq_gather: pure memory kernel, 2048 blocks (8 waves/SIMD): out=emb[idx].
// Predict: score 18-25us (theory right) or 30-35 (theory dead -> counters
// localize it); gather 6-10us at >50% HBM; total ~100-110.

typedef float f32x4 __attribute__((ext_vector_type(4)));
typedef long  l2    __attribute__((ext_vector_type(2)));
typedef _Float16 f16;
typedef f16 f16x8 __attribute__((ext_vector_type(8)));

#define D_DIM 256
#define K_CODES 1024

__device__ __forceinline__ long pack_fp8x8(float x0, float x1, float x2, float x3,
                                           float x4, float x5, float x6, float x7) {
    int w0 = __builtin_amdgcn_cvt_pk_fp8_f32(x0, x1, 0, false);
    w0     = __builtin_amdgcn_cvt_pk_fp8_f32(x2, x3, w0, true);
    int w1 = __builtin_amdgcn_cvt_pk_fp8_f32(x4, x5, 0, false);
    w1     = __builtin_amdgcn_cvt_pk_fp8_f32(x6, x7, w1, true);
    int2 p = {w0, w1};
    return __builtin_bit_cast(long, p);
}

// ---- Prep (verified r5-r9, unchanged): zero loss slot; emb -> fp8 (x1024) in
// fragment-slice-linear order (16 slices of 64 codes; chunk = ct*256 + t*64 +
// q*16 + m holds k-dims [t*64+q*8,+8) and [t*64+32+q*8,+8) of code
// sp*64+ct*16+m); eTe = 1024*||e||^2 fp32. grid 256 x 256.
__global__ __launch_bounds__(256) void vq_prep(const float* __restrict__ emb,
                                               char* __restrict__ emb8,
                                               float* __restrict__ eTe,
                                               float* __restrict__ loss_slot) {
    const int tid = threadIdx.x, wave = tid >> 6, lane = tid & 63;
    if (blockIdx.x == 0 && tid == 0) *loss_slot = 0.0f;

    if (blockIdx.x < 64) {
        int ch  = blockIdx.x * 256 + tid;     // 16384 chunks
        int sp  = ch >> 10;
        int rem = ch & 1023;
        int ct  = rem >> 8;
        int t   = (rem >> 6) & 3;
        int l   = rem & 63;
        int qq  = l >> 4, mm = l & 15;
        int code = sp * 64 + ct * 16 + mm;
        const float* p = emb + (size_t)code * D_DIM;
        int b0 = t * 64 + qq * 8;
        int b1 = b0 + 32;
        float4 v0 = *(const float4*)(p + b0);
        float4 v1 = *(const float4*)(p + b0 + 4);
        float4 v2 = *(const float4*)(p + b1);
        float4 v3 = *(const float4*)(p + b1 + 4);
        l2 out;
        out.x = pack_fp8x8(v0.x * 1024.f, v0.y * 1024.f, v0.z * 1024.f, v0.w * 1024.f,
                           v1.x * 1024.f, v1.y * 1024.f, v1.z * 1024.f, v1.w * 1024.f);
        out.y = pack_fp8x8(v2.x * 1024.f, v2.y * 1024.f, v2.z * 1024.f, v2.w * 1024.f,
                           v3.x * 1024.f, v3.y * 1024.f, v3.z * 1024.f, v3.w * 1024.f);
        *(l2*)(emb8 + (size_t)ch * 16) = out;
    }

    // eTe: one wave per code, 4 codes per block, pre-scaled by 1024.
    int code = blockIdx.x * 4 + wave;
    float4 v = ((const float4*)(emb + (size_t)code * D_DIM))[lane];
    float s = v.x * v.x + v.y * v.y + v.z * v.z + v.w * v.w;
    #pragma unroll
    for (int off = 32; off >= 1; off >>= 1) s += __shfl_down(s, off);
    if (lane == 0) eTe[code] = 1024.0f * s;
}

// ---- Score kernel ----------------------------------------------------------
__device__ __forceinline__ void loadB(l2 (&B)[16], const l2* __restrict__ gB,
                                      int sl, int lane) {
    const l2* p = gB + (size_t)sl * 1024 + lane;
    #pragma unroll
    for (int j = 0; j < 16; j++) B[j] = p[j * 64];   // 1KB coalesced each
}

// ete from LDS (lgkmcnt domain -- decoupled from the vmcnt B stream).
// (score, index) total order -> visit-order independent (slice rotation).
__device__ __forceinline__ void computeSlice(const l2 (&B)[16], const long (&A8)[8],
                                             const float* setep, int code0,
                                             int m, float (&best)[4], int (&bidx)[4]) {
    float ete[4];
    #pragma unroll
    for (int ct = 0; ct < 4; ct++) ete[ct] = setep[ct * 16 + m];   // ds_read

    f32x4 acc[4];
    #pragma unroll
    for (int ct = 0; ct < 4; ct++) acc[ct] = (f32x4){0.f, 0.f, 0.f, 0.f};

    __builtin_amdgcn_s_setprio(1);
    #pragma unroll
    for (int t = 0; t < 4; t++) {
        #pragma unroll
        for (int ct = 0; ct < 4; ct++) {
            acc[ct] = __builtin_amdgcn_mfma_f32_16x16x32_fp8_fp8(A8[2*t],   B[ct*4+t].x, acc[ct], 0, 0, 0);
            acc[ct] = __builtin_amdgcn_mfma_f32_16x16x32_fp8_fp8(A8[2*t+1], B[ct*4+t].y, acc[ct], 0, 0, 0);
        }
    }
    __builtin_amdgcn_s_setprio(0);

    #pragma unroll
    for (int ct = 0; ct < 4; ct++) {
        const int code = code0 + ct * 16 + m;
        #pragma unroll
        for (int r = 0; r < 4; r++) {
            float sc = fmaf(-2.0f, acc[ct][r], ete[ct]);
            if (sc < best[r] || (sc == best[r] && code < bidx[r])) {
                best[r] = sc; bidx[r] = code;
            }
        }
    }
}

// Wave-independent: wave = 16 FIXED rows x all 1024 codes; 2-deep register
// dbuf (no spill: ~110 live regs); slice order rotated per block.
// Output: idx[row] (128KB) + loss. NO gather/out-write here.
__global__ __launch_bounds__(256, 2) void vq_score(const float* __restrict__ z,
                                                   const char* __restrict__ emb8,
                                                   const float* __restrict__ eTe,
                                                   int* __restrict__ idx_out,
                                                   float* __restrict__ loss_slot,
                                                   float loss_scale) {
    __shared__ float s_ete[K_CODES];     // 4 KB
    __shared__ float s_red[4];

    const int tid  = threadIdx.x;
    const int w    = tid >> 6;
    const int lane = tid & 63;
    const int m    = lane & 15;        // A row / B col (code) / C col
    const int q    = lane >> 4;        // k-group / C row-group
    const int gw   = blockIdx.x * 4 + w;
    const size_t row0 = (size_t)gw * 16;
    const int sl0  = blockIdx.x & 15;  // slice rotation

    const l2* gB = (const l2*)emb8;
    l2 Ba[16], Bb[16];
    loadB(Ba, gB, sl0, lane);
    loadB(Bb, gB, (sl0 + 1) & 15, lane);

    // eTe -> LDS once (in-loop ete reads leave vmcnt alone).
    #pragma unroll
    for (int i = 0; i < 4; i++) s_ete[i * 256 + tid] = eTe[i * 256 + tid];

    // A fragments: this wave's 16 rows -> fp8 (verified r5-r9 layout):
    // lane (q,m) holds row m, k-dims [s*32+q*8, +8) per k-step s.
    long A8[8];
    float zsq = 0.f;
    {
        const float* zr = z + (row0 + m) * D_DIM;
        #pragma unroll
        for (int s = 0; s < 8; s++) {
            const float* p = zr + s * 32 + q * 8;
            float4 v0 = *(const float4*)p;
            float4 v1 = *(const float4*)(p + 4);
            zsq += v0.x * v0.x + v0.y * v0.y + v0.z * v0.z + v0.w * v0.w
                 + v1.x * v1.x + v1.y * v1.y + v1.z * v1.z + v1.w * v1.w;
            A8[s] = pack_fp8x8(v0.x, v0.y, v0.z, v0.w, v1.x, v1.y, v1.z, v1.w);
        }
    }
    __syncthreads();                    // s_ete table ready (one-time drain)

    float best[4];
    int   bidx[4];
    #pragma unroll
    for (int r = 0; r < 4; r++) { best[r] = __builtin_inff(); bidx[r] = 0x7fffffff; }

    // 16 slices; only VMEM in loop = the B stream (counted vmcnt).
    #pragma unroll 1
    for (int ii = 0; ii < 16; ii += 2) {
        const int s0 = (sl0 + ii) & 15, s1 = (sl0 + ii + 1) & 15;
        computeSlice(Ba, A8, &s_ete[s0 * 64], s0 * 64, m, best, bidx);
        if (ii + 2 < 16) loadB(Ba, gB, (sl0 + ii + 2) & 15, lane);
        computeSlice(Bb, A8, &s_ete[s1 * 64], s1 * 64, m, best, bidx);
        if (ii + 3 < 16) loadB(Bb, gB, (sl0 + ii + 3) & 15, lane);
    }

    // ONE cross-lane argmin per wave (xor-butterfly within each 16-lane
    // q-group; (score, index) total order -> order-independent result).
    #pragma unroll
    for (int r = 0; r < 4; r++) {
        float b  = best[r];
        int   bi = bidx[r];
        #pragma unroll
        for (int off = 8; off >= 1; off >>= 1) {
            float ob = __shfl_xor(b, off);
            int   oi = __shfl_xor(bi, off);
            if (ob < b || (ob == b && oi < bi)) { b = ob; bi = oi; }
        }
        best[r] = b; bidx[r] = bi;     // uniform within each 16-lane q-group
    }

    // idx + per-wave loss partial. Lane m==0 of q-group q owns rows q*4+r.
    float ls = 0.f;
    if (m == 0) {
        #pragma unroll
        for (int r = 0; r < 4; r++) {
            idx_out[row0 + q * 4 + r] = bidx[r];
            ls += best[r];
        }
    }
    ls += __shfl_down(ls, 32);         // lanes 0,16,32,48 -> lane 0
    ls += __shfl_down(ls, 16);
    #pragma unroll
    for (int off = 32; off >= 1; off >>= 1) zsq += __shfl_down(zsq, off);
    if (lane == 0) s_red[w] = zsq + ls * (1.0f / 1024.0f);
    __syncthreads();
    if (tid == 0)
        atomicAdd(loss_slot, (s_red[0] + s_red[1] + s_red[2] + s_red[3]) * loss_scale);
}

// ---- Gather kernel: out[row] = emb[idx[row]]. Pure memory op at full
// occupancy (2048 blocks = 8 waves/SIMD). One wave per row, 1KB coalesced.
__global__ __launch_bounds__(256) void vq_gather(const float* __restrict__ emb,
                                                 const int* __restrict__ idx,
                                                 float* __restrict__ out,
                                                 int nrows) {
    const int lane = threadIdx.x & 63;
    const int gw   = (blockIdx.x * 256 + threadIdx.x) >> 6;
    const int nw   = (gridDim.x * 256) >> 6;
    for (int row = gw; row < nrows; row += nw) {
        int bi = idx[row];             // uniform per wave -> broadcast
        float4 ev = *((const float4*)(emb + (size_t)bi * D_DIM) + lane);
        *((float4*)(out + (size_t)row * D_DIM) + lane) = ev;
    }
}

// ---- Fallback (round-2 structure, verified) — only if ws too small. --------
__global__ __launch_bounds__(256) void vq_prep_fb(const float* __restrict__ emb,
                                                  float* __restrict__ eTe,
                                                  float* __restrict__ loss_slot) {
    if (blockIdx.x == 0 && threadIdx.x == 0) *loss_slot = 0.0f;
    if (!eTe) return;
    int gtid = blockIdx.x * 256 + threadIdx.x;
    int code = gtid >> 6;
    int lane = threadIdx.x & 63;
    if (code >= K_CODES) return;
    float4 v = ((const float4*)(emb + (size_t)code * D_DIM))[lane];
    float s = v.x * v.x + v.y * v.y + v.z * v.z + v.w * v.w;
    #pragma unroll
    for (int off = 32; off >= 1; off >>= 1) s += __shfl_down(s, off);
    if (lane == 0) eTe[code] = s;
}

__global__ __launch_bounds__(128) void vq_main_fb(const float* __restrict__ z,
                                                  const float* __restrict__ emb,
                                                  const float* __restrict__ eTe_g,
                                                  float* __restrict__ out,
                                                  float* __restrict__ loss_slot,
                                                  float loss_scale) {
    __shared__ __align__(16) f16 sE[128 * D_DIM];
    __shared__ float s_ete[128];
    __shared__ int   s_idx2[128];
    __shared__ float s_red2[2];

    const int tid  = threadIdx.x;
    const int wave = tid >> 6;
    const int lane = tid & 63;
    const int m    = lane & 15;
    const int q    = lane >> 4;
    const size_t row0 = (size_t)blockIdx.x * 128 + (size_t)wave * 64;

    f16x8 A[4][8];
    #pragma unroll
    for (int st = 0; st < 4; st++) {
        const float* zr = z + (row0 + st * 16 + m) * D_DIM;
        #pragma unroll
        for (int s = 0; s < 8; s++) {
            const float* p = zr + s * 32 + q * 8;
            float4 v0 = *(const float4*)p;
            float4 v1 = *(const float4*)(p + 4);
            f16x8 a = {(f16)v0.x, (f16)v0.y, (f16)v0.z, (f16)v0.w,
                       (f16)v1.x, (f16)v1.y, (f16)v1.z, (f16)v1.w};
            A[st][s] = a;
        }
    }
    float best[4][4]; int bidx[4][4];
    #pragma unroll
    for (int st = 0; st < 4; st++)
        #pragma unroll
        for (int r = 0; r < 4; r++) { best[st][r] = __builtin_inff(); bidx[st][r] = 0; }

    const f16x8* sE8 = (const f16x8*)sE;
    #pragma unroll 1
    for (int sp = 0; sp < 8; sp++) {
        __syncthreads();
        if (eTe_g) s_ete[tid] = 1024.0f * eTe_g[sp * 128 + tid];
        else {
            const float* p = emb + (size_t)(sp * 128 + tid) * D_DIM;
            float ss = 0.f;
            for (int j = 0; j < D_DIM / 4; j++) {
                float4 v = ((const float4*)p)[j];
                ss += v.x * v.x + v.y * v.y + v.z * v.z + v.w * v.w;
            }
            s_ete[tid] = 1024.0f * ss;
        }
        const float* ebase = emb + (size_t)sp * 128 * D_DIM;
        #pragma unroll 4
        for (int it = 0; it < 32; it++) {
            int ch = it * 128 + tid;
            int cc = ((ch >> 9) << 4) | (ch & 15);
            int gg = (ch >> 4) & 31;
            const float* p = ebase + cc * D_DIM + gg * 8;
            float4 v0 = *(const float4*)p;
            float4 v1 = *(const float4*)(p + 4);
            f16x8 h = {(f16)(v0.x * 1024.f), (f16)(v0.y * 1024.f),
                       (f16)(v0.z * 1024.f), (f16)(v0.w * 1024.f),
                       (f16)(v1.x * 1024.f), (f16)(v1.y * 1024.f),
                       (f16)(v1.z * 1024.f), (f16)(v1.w * 1024.f)};
            *(f16x8*)(sE + (size_t)ch * 8) = h;
        }
        __syncthreads();
        for (int ct = 0; ct < 8; ct++) {
            f32x4 acc[4];
            #pragma unroll
            for (int st = 0; st < 4; st++) acc[st] = (f32x4){0.f, 0.f, 0.f, 0.f};
            #pragma unroll
            for (int s = 0; s < 8; s++) {
                f16x8 bh = sE8[ct * 512 + s * 64 + lane];
                #pragma unroll
                for (int st = 0; st < 4; st++)
                    acc[st] = __builtin_amdgcn_mfma_f32_16x16x32_f16(A[st][s], bh, acc[st], 0, 0, 0);
            }
            int codeL = ct * 16 + m;
            float ete = s_ete[codeL];
            int code  = sp * 128 + codeL;
            #pragma unroll
            for (int st = 0; st < 4; st++)
                #pragma unroll
                for (int r = 0; r < 4; r++) {
                    float sc = fmaf(-2.0f, acc[st][r], ete);
                    if (sc < best[st][r]) { best[st][r] = sc; bidx[st][r] = code; }
                }
        }
    }
    #pragma unroll
    for (int st = 0; st < 4; st++)
        #pragma unroll
        for (int r = 0; r < 4; r++) {
            float b = best[st][r]; int bi = bidx[st][r];
            #pragma unroll
            for (int off = 8; off >= 1; off >>= 1) {
                float ob = __shfl_xor(b, off);
                int   oi = __shfl_xor(bi, off);
                if (ob < b || (ob == b && oi < bi)) { b = ob; bi = oi; }
            }
            if (m == 0) s_idx2[wave * 64 + st * 16 + q * 4 + r] = bi;
        }
    __syncthreads();
    float lsum = 0.f;
    #pragma unroll
    for (int st = 0; st < 4; st++) {
        int rl = wave * 64 + st * 16 + m;
        int idxv = s_idx2[rl];
        const float* er = emb + (size_t)idxv * D_DIM;
        float* orow = out + ((size_t)blockIdx.x * 128 + rl) * D_DIM;
        #pragma unroll
        for (int s = 0; s < 8; s++) {
            int dd = s * 32 + q * 8;
            float4 e0 = *(const float4*)(er + dd);
            float4 e1 = *(const float4*)(er + dd + 4);
            *(float4*)(orow + dd)     = e0;
            *(float4*)(orow + dd + 4) = e1;
            f16x8 a = A[st][s];
            float d0 = e0.x - (float)a[0], d1 = e0.y - (float)a[1];
            float d2 = e0.z - (float)a[2], d3 = e0.w - (float)a[3];
            float d4 = e1.x - (float)a[4], d5 = e1.y - (float)a[5];
            float d6 = e1.z - (float)a[6], d7 = e1.w - (float)a[7];
            lsum += d0*d0 + d1*d1 + d2*d2 + d3*d3 + d4*d4 + d5*d5 + d6*d6 + d7*d7;
        }
    }
    #pragma unroll
    for (int off = 32; off >= 1; off >>= 1) lsum += __shfl_down(lsum, off);
    if (lane == 0) s_red2[wave] = lsum;
    __syncthreads();
    if (tid == 0) atomicAdd(loss_slot, (s_red2[0] + s_red2[1]) * loss_scale);
}

extern "C" void kernel_launch(void* const* d_in, const int* in_sizes, int n_in,
                              void* d_out, int out_size, void* d_ws, size_t ws_size,
                              hipStream_t stream) {
    const float* z   = (const float*)d_in[0];
    const float* emb = (const float*)d_in[1];
    float* out = (float*)d_out;
    const int NROWS = in_sizes[0] / D_DIM;              // 32768
    float* loss_slot = out + (size_t)in_sizes[0];
    float loss_scale = 1.25f / (float)in_sizes[0];

    const size_t emb8_bytes = (size_t)K_CODES * D_DIM;  // 256 KB
    const size_t ete_bytes  = K_CODES * sizeof(float);  // 4 KB
    const size_t idx_bytes  = (size_t)NROWS * sizeof(int);  // 128 KB
    const size_t need = emb8_bytes + ete_bytes + idx_bytes;

    if (ws_size >= need) {
        char*  emb8 = (char*)d_ws;
        float* eTe  = (float*)((char*)d_ws + emb8_bytes);
        int*   idx  = (int*)((char*)d_ws + emb8_bytes + ete_bytes);
        vq_prep<<<256, 256, 0, stream>>>(emb, emb8, eTe, loss_slot);
        vq_score<<<NROWS / 64, 256, 0, stream>>>(z, emb8, eTe, idx, loss_slot, loss_scale);
        vq_gather<<<2048, 256, 0, stream>>>(emb, idx, out, NROWS);
    } else {
        float* eTe = (ws_size >= ete_bytes) ? (float*)d_ws : nullptr;
        vq_prep_fb<<<K_CODES / 4, 256, 0, stream>>>(emb, eTe, loss_slot);
        vq_main_fb<<<NROWS / 128, 128, 0, stream>>>(z, emb, eTe, out, loss_slot, loss_scale);
    }
}